// Round 1
// baseline (72.525 us; speedup 1.0000x reference)
//
#include <hip/hip_runtime.h>
#include <stdint.h>

#define NBATCH 2
#define NBOX 8400
#define NCLS 80
#define NP 32
#define HPX 160
#define KDET 100
#define VTOT (NBOX*NCLS)          // 672000
#define ROWLEN (6 + HPX*HPX)      // 25606
#define NBINS 2048
#define CANDCAP 4096

// ws layout (bytes):
//     0 : uint hist[2][NBINS]   (16384)  <- zeroed each launch
// 16384 : uint candCount[2]     (8)      <- zeroed each launch
// 16400 : int  tbc[4]           (16)     tb[2], cAbove[2]
// 16416 : ull  cand[2][CANDCAP] (65536)
// 81952 : float roi[200][4]     (3200)
// 85152 : int  nbox[200]        (800)

__device__ __forceinline__ unsigned int fkey(float f) {
  unsigned int u = __float_as_uint(f);
  return (u & 0x80000000u) ? ~u : (u | 0x80000000u);
}

__global__ __launch_bounds__(256) void k_hist(const float* __restrict__ scores,
                                              unsigned int* __restrict__ hist) {
  int b = blockIdx.y;
  __shared__ unsigned int lh[NBINS];
  for (int i = threadIdx.x; i < NBINS; i += 256) lh[i] = 0;
  __syncthreads();
  const float* s = scores + (size_t)b * VTOT;
  int stride = gridDim.x * 256;
  for (int i = blockIdx.x * 256 + threadIdx.x; i < VTOT; i += stride)
    atomicAdd(&lh[fkey(s[i]) >> 21], 1u);
  __syncthreads();
  unsigned int* gh = hist + b * NBINS;
  for (int i = threadIdx.x; i < NBINS; i += 256)
    if (lh[i]) atomicAdd(&gh[i], lh[i]);
}

__global__ __launch_bounds__(256) void k_findtb(const unsigned int* __restrict__ hist,
                                                int* __restrict__ tbc) {
  int b = blockIdx.x;
  const unsigned int* gh = hist + b * NBINS;
  __shared__ unsigned int buf[256];
  __shared__ int jstarS;
  __shared__ unsigned int sufAfterS;
  int tid = threadIdx.x;
  unsigned int s = 0;
#pragma unroll
  for (int k = 0; k < NBINS/256; ++k) s += gh[tid*(NBINS/256) + k];
  buf[tid] = s;
  __syncthreads();
  for (int off = 1; off < 256; off <<= 1) {
    unsigned int add = (tid + off < 256) ? buf[tid + off] : 0u;
    __syncthreads();
    buf[tid] += add;
    __syncthreads();
  }
  unsigned int s1 = buf[tid];
  unsigned int s2 = (tid < 255) ? buf[tid + 1] : 0u;
  if (s1 >= KDET && s2 < KDET) { jstarS = tid; sufAfterS = s2; }
  __syncthreads();
  if (tid == 0) {
    int g = jstarS;
    unsigned int cum = sufAfterS;
    int tb = g * (NBINS/256);
    unsigned int cab = 0;
    for (int bin = g*(NBINS/256) + (NBINS/256) - 1; bin >= g*(NBINS/256); --bin) {
      unsigned int h = gh[bin];
      if (cum + h >= KDET) { tb = bin; cab = cum; break; }
      cum += h;
    }
    tbc[b] = tb;
    tbc[2 + b] = (int)cab;
  }
}

__global__ __launch_bounds__(256) void k_collect(const float* __restrict__ scores,
                                                 const int* __restrict__ tbc,
                                                 unsigned int* __restrict__ candCount,
                                                 unsigned long long* __restrict__ cand) {
  int b = blockIdx.y;
  int tb = tbc[b];
  const float* s = scores + (size_t)b * VTOT;
  unsigned long long* cb = cand + (size_t)b * CANDCAP;
  int stride = gridDim.x * 256;
  for (int i = blockIdx.x * 256 + threadIdx.x; i < VTOT; i += stride) {
    unsigned int key = fkey(s[i]);
    if ((int)(key >> 21) >= tb) {
      unsigned int pos = atomicAdd(&candCount[b], 1u);
      if (pos < CANDCAP) cb[pos] = ((unsigned long long)key << 32) | (unsigned int)(~(unsigned int)i);
    }
  }
}

__global__ __launch_bounds__(1024) void k_final(const unsigned int* __restrict__ candCount,
                                                const unsigned long long* __restrict__ cand,
                                                const float* __restrict__ boxes,
                                                float* __restrict__ out,
                                                float* __restrict__ roi,
                                                int* __restrict__ nboxArr) {
  int b = blockIdx.x;
  __shared__ unsigned long long sh[CANDCAP];
  int c = (int)min(candCount[b], (unsigned int)CANDCAP);
  int n = 128;
  while (n < c) n <<= 1;
  for (int i = threadIdx.x; i < n; i += 1024)
    sh[i] = (i < c) ? cand[(size_t)b * CANDCAP + i] : 0ull;
  __syncthreads();
  for (int k = 2; k <= n; k <<= 1) {
    for (int j = k >> 1; j > 0; j >>= 1) {
      for (int i = threadIdx.x; i < n; i += 1024) {
        int ixj = i ^ j;
        if (ixj > i) {
          unsigned long long a = sh[i], bb = sh[ixj];
          bool desc = ((i & k) == 0);
          if (desc ? (a < bb) : (a > bb)) { sh[i] = bb; sh[ixj] = a; }
        }
      }
      __syncthreads();
    }
  }
  if (threadIdx.x < KDET) {
    int i = threadIdx.x;
    unsigned long long rec = sh[i];
    unsigned int key = (unsigned int)(rec >> 32);
    unsigned int idx = ~((unsigned int)rec);
    unsigned int u = (key & 0x80000000u) ? (key & 0x7FFFFFFFu) : ~key;
    float logit = __uint_as_float(u);
    float score = 1.0f / (1.0f + expf(-logit));
    int nb = (int)(idx / NCLS);
    int lab = (int)(idx - (unsigned int)nb * NCLS);
    const float* bp = boxes + ((size_t)b * NBOX + nb) * 4;
    float cx = bp[0], cy = bp[1], w = bp[2], h = bp[3];
    float x1 = (cx - 0.5f*w) * 640.0f;
    float y1 = (cy - 0.5f*h) * 640.0f;
    float x2 = (cx + 0.5f*w) * 640.0f;
    float y2 = (cy + 0.5f*h) * 640.0f;
    size_t row = ((size_t)b * KDET + i) * ROWLEN;
    out[row+0] = x1; out[row+1] = y1; out[row+2] = x2; out[row+3] = y2;
    out[row+4] = score; out[row+5] = (float)lab;
    int t = b * KDET + i;
    roi[t*4+0] = x1 * 0.25f;
    roi[t*4+1] = y1 * 0.25f;
    roi[t*4+2] = x2 * 0.25f;
    roi[t*4+3] = y2 * 0.25f;
    nboxArr[t] = nb;
  }
}

// one block = one detection t x 16 output rows. Compute scalar field
// S[y][x] = sum_p m_p * protos[b,p,y,x] over the needed proto region (<=18 rows),
// then bilinear-sample it (einsum commutes with bilinear interp).
__global__ __launch_bounds__(256) void k_mask(const float* __restrict__ protos,
                                              const float* __restrict__ masks,
                                              const float* __restrict__ roi,
                                              const int* __restrict__ nboxArr,
                                              const float* __restrict__ bias,
                                              float* __restrict__ out) {
  int t = blockIdx.y;
  int chunk = blockIdx.x;
  int b = t / KDET;
  int i = t - b * KDET;
  __shared__ float m[NP];
  __shared__ float S[18][HPX];
  __shared__ float roiS[4];
  __shared__ int nbS;
  if (threadIdx.x == 0) nbS = nboxArr[t];
  if (threadIdx.x < 4) roiS[threadIdx.x] = roi[t*4 + threadIdx.x];
  __syncthreads();
  if (threadIdx.x < NP)
    m[threadIdx.x] = masks[((size_t)b * NBOX + nbS) * NP + threadIdx.x];
  float rx1 = roiS[0], ry1 = roiS[1], rx2 = roiS[2], ry2 = roiS[3];
  float bin_h = (ry2 - ry1) * (1.0f/HPX);
  float bin_w = (rx2 - rx1) * (1.0f/HPX);
  int h0 = chunk * 16;
  float ys_min = fminf(fmaxf(ry1 + (h0 + 0.5f)*bin_h - 0.5f, 0.0f), 159.0f);
  float ys_max = fminf(fmaxf(ry1 + (h0 + 15.5f)*bin_h - 0.5f, 0.0f), 159.0f);
  int ryA = (int)ys_min;
  int ryB = min((int)ys_max + 1, HPX-1);
  float xs_min = fminf(fmaxf(rx1 + 0.5f*bin_w - 0.5f, 0.0f), 159.0f);
  float xs_max = fminf(fmaxf(rx1 + 159.5f*bin_w - 0.5f, 0.0f), 159.0f);
  int cxA = ((int)xs_min) & ~3;
  int cxB = min((int)xs_max + 1, HPX-1);
  int Rr = ryB - ryA + 1;
  int qC = (cxB - cxA + 4) >> 2;      // ceil(width/4) float4 quads per row
  __syncthreads();                    // m[] ready
  int RC = Rr * qC;
  const float* pb = protos + (size_t)b * NP * HPX * HPX;
  for (int q = threadIdx.x; q < RC; q += 256) {
    int r = q / qC;
    int cq = q - r * qC;
    int ry = ryA + r;
    int c4 = cxA + (cq << 2);
    if (c4 > HPX-4) c4 = HPX-4;       // clamp last quad (dup writes are identical)
    const float* pp = pb + (size_t)ry * HPX + c4;
    float ax = 0.f, ay = 0.f, az = 0.f, aw = 0.f;
#pragma unroll
    for (int p = 0; p < NP; ++p) {
      float4 v = *reinterpret_cast<const float4*>(pp + (size_t)p * (HPX*HPX));
      float mv = m[p];
      ax += mv * v.x; ay += mv * v.y; az += mv * v.z; aw += mv * v.w;
    }
    float4 sv; sv.x = ax; sv.y = ay; sv.z = az; sv.w = aw;
    *reinterpret_cast<float4*>(&S[r][c4 - cxA]) = sv;
  }
  __syncthreads();
  float bv = bias[0];
  size_t base = ((size_t)b * KDET + i) * ROWLEN + 6 + (size_t)h0 * HPX;
#pragma unroll
  for (int k = 0; k < 10; ++k) {
    int pix = threadIdx.x + k * 256;  // 16*160 = 2560 = 10*256 exactly
    int hl = pix / HPX;
    int w = pix - hl * HPX;
    int h = h0 + hl;
    float ys = fminf(fmaxf(ry1 + (h + 0.5f)*bin_h - 0.5f, 0.0f), 159.0f);
    float xs = fminf(fmaxf(rx1 + (w + 0.5f)*bin_w - 0.5f, 0.0f), 159.0f);
    int y0 = (int)ys, x0 = (int)xs;
    int y1i = min(y0 + 1, HPX-1), x1i = min(x0 + 1, HPX-1);
    float ly = ys - (float)y0, lx = xs - (float)x0;
    float v00 = S[y0 - ryA][x0 - cxA];
    float v01 = S[y0 - ryA][x1i - cxA];
    float v10 = S[y1i - ryA][x0 - cxA];
    float v11 = S[y1i - ryA][x1i - cxA];
    float vtop = v00 + lx * (v01 - v00);
    float vbot = v10 + lx * (v11 - v10);
    float val = vtop + ly * (vbot - vtop);
    out[base + pix] = val + bv;
  }
}

extern "C" void kernel_launch(void* const* d_in, const int* in_sizes, int n_in,
                              void* d_out, int out_size, void* d_ws, size_t ws_size,
                              hipStream_t stream) {
  (void)in_sizes; (void)n_in; (void)out_size; (void)ws_size;
  const float* boxes  = (const float*)d_in[0];
  const float* scores = (const float*)d_in[1];
  const float* protos = (const float*)d_in[2];
  const float* masks  = (const float*)d_in[3];
  const float* bias   = (const float*)d_in[4];
  float* out = (float*)d_out;
  char* ws = (char*)d_ws;

  unsigned int* hist            = (unsigned int*)(ws);
  unsigned int* candCount       = (unsigned int*)(ws + 16384);
  int* tbc                      = (int*)(ws + 16400);
  unsigned long long* cand      = (unsigned long long*)(ws + 16416);
  float* roi                    = (float*)(ws + 81952);
  int* nboxArr                  = (int*)(ws + 85152);

  hipMemsetAsync(ws, 0, 16392, stream);  // hist + candCount
  k_hist<<<dim3(64, 2), 256, 0, stream>>>(scores, hist);
  k_findtb<<<2, 256, 0, stream>>>(hist, tbc);
  k_collect<<<dim3(64, 2), 256, 0, stream>>>(scores, tbc, candCount, cand);
  k_final<<<2, 1024, 0, stream>>>(candCount, cand, boxes, out, roi, nboxArr);
  k_mask<<<dim3(10, 200), 256, 0, stream>>>(protos, masks, roi, nboxArr, bias, out);
}

// Round 2
// 68.910 us; speedup vs baseline: 1.0525x; 1.0525x over previous
//
#include <hip/hip_runtime.h>
#include <stdint.h>

#define NBATCH 2
#define NBOX 8400
#define NCLS 80
#define NP 32
#define HPX 160
#define KDET 100
#define VTOT (NBOX*NCLS)          // 672000
#define ROWLEN (6 + HPX*HPX)      // 25606
#define NBINS 2048
#define CANDCAP 4096

// ws layout (bytes):
//     0 : uint hist[2][NBINS]   (16384)  <- zeroed by k_zero each launch
// 16384 : uint candCount[2]     (8)      <- zeroed by k_zero each launch
// 16400 : int  tbc[4]           (16)     tb[2], cAbove[2]
// 16416 : ull  cand[2][CANDCAP] (65536)
// 81952 : float roi[200][4]     (3200)
// 85152 : int  nbox[200]        (800)

__device__ __forceinline__ unsigned int fkey(float f) {
  unsigned int u = __float_as_uint(f);
  return (u & 0x80000000u) ? ~u : (u | 0x80000000u);
}

__global__ __launch_bounds__(256) void k_zero(unsigned int* __restrict__ p) {
  // hist (2*2048) + candCount (2) = 4098 dwords
  for (int i = threadIdx.x; i < 4098; i += 256) p[i] = 0u;
}

__global__ __launch_bounds__(256) void k_hist(const float* __restrict__ scores,
                                              unsigned int* __restrict__ hist) {
  int b = blockIdx.y;
  __shared__ unsigned int lh[NBINS];
  for (int i = threadIdx.x; i < NBINS; i += 256) lh[i] = 0;
  __syncthreads();
  const float* s = scores + (size_t)b * VTOT;
  int stride = gridDim.x * 256;
  for (int i = blockIdx.x * 256 + threadIdx.x; i < VTOT; i += stride)
    atomicAdd(&lh[fkey(s[i]) >> 21], 1u);
  __syncthreads();
  unsigned int* gh = hist + b * NBINS;
  for (int i = threadIdx.x; i < NBINS; i += 256)
    if (lh[i]) atomicAdd(&gh[i], lh[i]);
}

__global__ __launch_bounds__(256) void k_findtb(const unsigned int* __restrict__ hist,
                                                int* __restrict__ tbc) {
  int b = blockIdx.x;
  const unsigned int* gh = hist + b * NBINS;
  __shared__ unsigned int buf[256];
  __shared__ int jstarS;
  __shared__ unsigned int sufAfterS;
  int tid = threadIdx.x;
  unsigned int s = 0;
#pragma unroll
  for (int k = 0; k < NBINS/256; ++k) s += gh[tid*(NBINS/256) + k];
  buf[tid] = s;
  __syncthreads();
  for (int off = 1; off < 256; off <<= 1) {
    unsigned int add = (tid + off < 256) ? buf[tid + off] : 0u;
    __syncthreads();
    buf[tid] += add;
    __syncthreads();
  }
  unsigned int s1 = buf[tid];
  unsigned int s2 = (tid < 255) ? buf[tid + 1] : 0u;
  if (s1 >= KDET && s2 < KDET) { jstarS = tid; sufAfterS = s2; }
  __syncthreads();
  if (tid == 0) {
    int g = jstarS;
    unsigned int cum = sufAfterS;
    int tb = g * (NBINS/256);
    for (int bin = g*(NBINS/256) + (NBINS/256) - 1; bin >= g*(NBINS/256); --bin) {
      unsigned int h = gh[bin];
      if (cum + h >= KDET) { tb = bin; break; }
      cum += h;
    }
    tbc[b] = tb;
  }
}

__global__ __launch_bounds__(256) void k_collect(const float* __restrict__ scores,
                                                 const int* __restrict__ tbc,
                                                 unsigned int* __restrict__ candCount,
                                                 unsigned long long* __restrict__ cand) {
  int b = blockIdx.y;
  int tb = tbc[b];
  const float* s = scores + (size_t)b * VTOT;
  unsigned long long* cb = cand + (size_t)b * CANDCAP;
  int stride = gridDim.x * 256;
  for (int i = blockIdx.x * 256 + threadIdx.x; i < VTOT; i += stride) {
    unsigned int key = fkey(s[i]);
    if ((int)(key >> 21) >= tb) {
      unsigned int pos = atomicAdd(&candCount[b], 1u);
      if (pos < CANDCAP) cb[pos] = ((unsigned long long)key << 32) | (unsigned int)(~(unsigned int)i);
    }
  }
}

// Rank-selection: candidate keys (key<<32)|~idx are unique, so each candidate's
// exact rank = #candidates greater than it. rank < KDET -> emit to slot `rank`.
// Zero barriers after the LDS load (vs ~36 for bitonic).
__global__ __launch_bounds__(256) void k_final(const unsigned int* __restrict__ candCount,
                                               const unsigned long long* __restrict__ cand,
                                               const float* __restrict__ boxes,
                                               float* __restrict__ out,
                                               float* __restrict__ roi,
                                               int* __restrict__ nboxArr) {
  int b = blockIdx.x;
  __shared__ unsigned long long sh[CANDCAP];
  int c = (int)min(candCount[b], (unsigned int)CANDCAP);
  for (int i = threadIdx.x; i < c; i += 256)
    sh[i] = cand[(size_t)b * CANDCAP + i];
  __syncthreads();
  for (int i = threadIdx.x; i < c; i += 256) {
    unsigned long long me = sh[i];
    int rank = 0;
    for (int j = 0; j < c; ++j) rank += (sh[j] > me) ? 1 : 0;
    if (rank < KDET) {
      unsigned int key = (unsigned int)(me >> 32);
      unsigned int idx = ~((unsigned int)me);
      unsigned int u = (key & 0x80000000u) ? (key & 0x7FFFFFFFu) : ~key;
      float logit = __uint_as_float(u);
      float score = 1.0f / (1.0f + expf(-logit));
      int nb = (int)(idx / NCLS);
      int lab = (int)(idx - (unsigned int)nb * NCLS);
      const float* bp = boxes + ((size_t)b * NBOX + nb) * 4;
      float cx = bp[0], cy = bp[1], w = bp[2], h = bp[3];
      float x1 = (cx - 0.5f*w) * 640.0f;
      float y1 = (cy - 0.5f*h) * 640.0f;
      float x2 = (cx + 0.5f*w) * 640.0f;
      float y2 = (cy + 0.5f*h) * 640.0f;
      size_t row = ((size_t)b * KDET + rank) * ROWLEN;
      out[row+0] = x1; out[row+1] = y1; out[row+2] = x2; out[row+3] = y2;
      out[row+4] = score; out[row+5] = (float)lab;
      int t = b * KDET + rank;
      roi[t*4+0] = x1 * 0.25f;
      roi[t*4+1] = y1 * 0.25f;
      roi[t*4+2] = x2 * 0.25f;
      roi[t*4+3] = y2 * 0.25f;
      nboxArr[t] = nb;
    }
  }
}

// one block = one detection t x 16 output rows. Compute scalar field
// S[y][x] = sum_p m_p * protos[b,p,y,x] over the needed proto region (<=18 rows),
// then bilinear-sample it (einsum commutes with bilinear interp).
__global__ __launch_bounds__(256) void k_mask(const float* __restrict__ protos,
                                              const float* __restrict__ masks,
                                              const float* __restrict__ roi,
                                              const int* __restrict__ nboxArr,
                                              const float* __restrict__ bias,
                                              float* __restrict__ out) {
  int t = blockIdx.y;
  int chunk = blockIdx.x;
  int b = t / KDET;
  int i = t - b * KDET;
  __shared__ float m[NP];
  __shared__ float S[18][HPX];
  __shared__ float roiS[4];
  __shared__ int nbS;
  if (threadIdx.x == 0) nbS = nboxArr[t];
  if (threadIdx.x < 4) roiS[threadIdx.x] = roi[t*4 + threadIdx.x];
  __syncthreads();
  if (threadIdx.x < NP)
    m[threadIdx.x] = masks[((size_t)b * NBOX + nbS) * NP + threadIdx.x];
  float rx1 = roiS[0], ry1 = roiS[1], rx2 = roiS[2], ry2 = roiS[3];
  float bin_h = (ry2 - ry1) * (1.0f/HPX);
  float bin_w = (rx2 - rx1) * (1.0f/HPX);
  int h0 = chunk * 16;
  float ys_min = fminf(fmaxf(ry1 + (h0 + 0.5f)*bin_h - 0.5f, 0.0f), 159.0f);
  float ys_max = fminf(fmaxf(ry1 + (h0 + 15.5f)*bin_h - 0.5f, 0.0f), 159.0f);
  int ryA = (int)ys_min;
  int ryB = min((int)ys_max + 1, HPX-1);
  float xs_min = fminf(fmaxf(rx1 + 0.5f*bin_w - 0.5f, 0.0f), 159.0f);
  float xs_max = fminf(fmaxf(rx1 + 159.5f*bin_w - 0.5f, 0.0f), 159.0f);
  int cxA = ((int)xs_min) & ~3;
  int cxB = min((int)xs_max + 1, HPX-1);
  int Rr = ryB - ryA + 1;
  int qC = (cxB - cxA + 4) >> 2;      // ceil(width/4) float4 quads per row
  __syncthreads();                    // m[] ready
  int RC = Rr * qC;
  const float* pb = protos + (size_t)b * NP * HPX * HPX;
  for (int q = threadIdx.x; q < RC; q += 256) {
    int r = q / qC;
    int cq = q - r * qC;
    int ry = ryA + r;
    int c4 = cxA + (cq << 2);
    if (c4 > HPX-4) c4 = HPX-4;       // clamp last quad (dup writes are identical)
    const float* pp = pb + (size_t)ry * HPX + c4;
    float ax = 0.f, ay = 0.f, az = 0.f, aw = 0.f;
#pragma unroll
    for (int p = 0; p < NP; ++p) {
      float4 v = *reinterpret_cast<const float4*>(pp + (size_t)p * (HPX*HPX));
      float mv = m[p];
      ax += mv * v.x; ay += mv * v.y; az += mv * v.z; aw += mv * v.w;
    }
    float4 sv; sv.x = ax; sv.y = ay; sv.z = az; sv.w = aw;
    *reinterpret_cast<float4*>(&S[r][c4 - cxA]) = sv;
  }
  __syncthreads();
  float bv = bias[0];
  size_t base = ((size_t)b * KDET + i) * ROWLEN + 6 + (size_t)h0 * HPX;
#pragma unroll
  for (int k = 0; k < 10; ++k) {
    int pix = threadIdx.x + k * 256;  // 16*160 = 2560 = 10*256 exactly
    int hl = pix / HPX;
    int w = pix - hl * HPX;
    int h = h0 + hl;
    float ys = fminf(fmaxf(ry1 + (h + 0.5f)*bin_h - 0.5f, 0.0f), 159.0f);
    float xs = fminf(fmaxf(rx1 + (w + 0.5f)*bin_w - 0.5f, 0.0f), 159.0f);
    int y0 = (int)ys, x0 = (int)xs;
    int y1i = min(y0 + 1, HPX-1), x1i = min(x0 + 1, HPX-1);
    float ly = ys - (float)y0, lx = xs - (float)x0;
    float v00 = S[y0 - ryA][x0 - cxA];
    float v01 = S[y0 - ryA][x1i - cxA];
    float v10 = S[y1i - ryA][x0 - cxA];
    float v11 = S[y1i - ryA][x1i - cxA];
    float vtop = v00 + lx * (v01 - v00);
    float vbot = v10 + lx * (v11 - v10);
    float val = vtop + ly * (vbot - vtop);
    out[base + pix] = val + bv;
  }
}

extern "C" void kernel_launch(void* const* d_in, const int* in_sizes, int n_in,
                              void* d_out, int out_size, void* d_ws, size_t ws_size,
                              hipStream_t stream) {
  (void)in_sizes; (void)n_in; (void)out_size; (void)ws_size;
  const float* boxes  = (const float*)d_in[0];
  const float* scores = (const float*)d_in[1];
  const float* protos = (const float*)d_in[2];
  const float* masks  = (const float*)d_in[3];
  const float* bias   = (const float*)d_in[4];
  float* out = (float*)d_out;
  char* ws = (char*)d_ws;

  unsigned int* hist            = (unsigned int*)(ws);
  unsigned int* candCount       = (unsigned int*)(ws + 16384);
  int* tbc                      = (int*)(ws + 16400);
  unsigned long long* cand      = (unsigned long long*)(ws + 16416);
  float* roi                    = (float*)(ws + 81952);
  int* nboxArr                  = (int*)(ws + 85152);

  k_zero<<<1, 256, 0, stream>>>((unsigned int*)ws);
  k_hist<<<dim3(64, 2), 256, 0, stream>>>(scores, hist);
  k_findtb<<<2, 256, 0, stream>>>(hist, tbc);
  k_collect<<<dim3(64, 2), 256, 0, stream>>>(scores, tbc, candCount, cand);
  k_final<<<2, 256, 0, stream>>>(candCount, cand, boxes, out, roi, nboxArr);
  k_mask<<<dim3(10, 200), 256, 0, stream>>>(protos, masks, roi, nboxArr, bias, out);
}